// Round 10
// baseline (307.269 us; speedup 1.0000x reference)
//
#include <hip/hip_runtime.h>
#include <hip/hip_bf16.h>

// Cross-attention: fp32 in -> fp32 out, bf16 MFMA compute.
// B=4 L=4096 R=512 DIM=1024 H=16 DH=64, scale = 1/8.
// R10 = R9 resubmit (container infra failure, same signature as R1).
// Q-proj and O-proj on the 8-phase 256^2 template (T3+T4+T5+T2):
// 512 thr / 8 waves (2Mx4N), BK=64 as 2 k-halves, 128KB LDS double-buffer,
// counted vmcnt(8) (never 0 in steady state), XOR-swizzled LDS (both sides).
// Grid = 256 wgs = exactly 1 block/CU, no tail. KV stays on the R8 128^2
// kernel; attn/prep byte-identical (V through LDS -- R5 proved direct-global
// PV is 3x worse).
#define DIMC 1024
#define HEADS 16
#define DHEAD 64
#define LQ 4096
#define RK 512
#define BATCH 4

// 0.125 * log2(e): folded into the Q projection so softmax runs in exp2 domain
#define QSCALE 0.18033688011112042f

using bf16x8  = __attribute__((ext_vector_type(8))) __bf16;
using short4v = __attribute__((ext_vector_type(4))) short;
using f32x4   = __attribute__((ext_vector_type(4))) float;

__device__ inline ushort f2bf(float f) {
  __hip_bfloat16 h = __float2bfloat16(f);
  return *reinterpret_cast<ushort*>(&h);
}

__device__ inline float exp2_fast(float x) {
  float r; asm("v_exp_f32 %0, %1" : "=v"(r) : "v"(x)); return r;
}

// ---------------- prep: cvt_in + transpose_w merged --------------------------
__global__ __launch_bounds__(256) void prep(const float* __restrict__ x,
    const float* __restrict__ ctx, ushort* __restrict__ xb,
    ushort* __restrict__ ctxb,
    const float* __restrict__ W0, const float* __restrict__ W1,
    const float* __restrict__ W2, const float* __restrict__ W3,
    ushort* __restrict__ D0, ushort* __restrict__ D1,
    ushort* __restrict__ D2, ushort* __restrict__ D3) {
  __shared__ ushort tile[32][33];
  const int bid = blockIdx.x;
  if (bid < 9216) {
    size_t i = ((size_t)bid * 256 + threadIdx.x) * 8;
    const float* src; ushort* dst; size_t off;
    if (i < (size_t)16777216) { src = x; dst = xb; off = i; }
    else { src = ctx; dst = ctxb; off = i - 16777216; }
    float4 a = *(const float4*)(src + off);
    float4 b = *(const float4*)(src + off + 4);
    ushort u[8];
    u[0]=f2bf(a.x); u[1]=f2bf(a.y); u[2]=f2bf(a.z); u[3]=f2bf(a.w);
    u[4]=f2bf(b.x); u[5]=f2bf(b.y); u[6]=f2bf(b.z); u[7]=f2bf(b.w);
    *(uint4*)(dst + off) = *(const uint4*)u;
    return;
  }
  const int tb = bid - 9216;            // 0..4095
  const int z = tb >> 10, rem = tb & 1023;
  const int bx = rem & 31, by = rem >> 5;
  const float* src = (z == 0) ? W0 : (z == 1) ? W1 : (z == 2) ? W2 : W3;
  ushort* dst = (z == 0) ? D0 : (z == 1) ? D1 : (z == 2) ? D2 : D3;
  const int tx = threadIdx.x & 31, ty = threadIdx.x >> 5; // 32 x 8
  const int xg = bx * 32 + tx;
  #pragma unroll
  for (int j = 0; j < 32; j += 8)
    tile[ty + j][tx] = f2bf(src[(size_t)(by * 32 + ty + j) * DIMC + xg]);
  __syncthreads();
  const int xo = by * 32 + tx;
  #pragma unroll
  for (int j = 0; j < 32; j += 8)
    dst[(size_t)(bx * 32 + ty + j) * DIMC + xo] = tile[tx][ty + j];
}

// ---------------- KV projection GEMM (R8 128^2 BK=64, proven) ----------------
// 2048x2048x1024: n<1024 -> K into Kw; n>=1024 -> V transposed per (b,h).
__global__ __launch_bounds__(256, 4) void gemm_kv(const ushort* __restrict__ A,
    const ushort* __restrict__ Bt, ushort* __restrict__ Kw,
    ushort* __restrict__ Vt) {
  __shared__ ushort As[128 * 64];
  __shared__ ushort Bs[128 * 64];
  const int tid  = threadIdx.x;
  const int wave = tid >> 6, lane = tid & 63;
  const int lr = lane & 15, quad = lane >> 4;
  const int bid = blockIdx.y * 16 + blockIdx.x;      // 256 wgs
  const int swz = (bid & 7) * 32 + (bid >> 3);
  const size_t m0 = (size_t)(swz >> 4) * 128;        // 0..2047
  const size_t n0 = (size_t)(swz & 15) * 128;        // 0..2047
  const int wm = (wave >> 1) * 64, wn = (wave & 1) * 64;
  const int rsw = lr & 7;
  f32x4 acc[4][4] = {};
  for (int k0 = 0; k0 < DIMC; k0 += 64) {
    __syncthreads();
    #pragma unroll
    for (int t = 0; t < 4; ++t) {
      int c = (wave * 4 + t) * 64 + lane;
      int row = c >> 3, cc = c & 7;
      int col = (cc ^ (row & 7)) * 8;
      const ushort* ga = A  + (m0 + row) * DIMC + k0 + col;
      const ushort* gb = Bt + (n0 + row) * DIMC + k0 + col;
      __builtin_amdgcn_global_load_lds(
          (__attribute__((address_space(1))) void*)ga,
          (__attribute__((address_space(3))) void*)(As + (size_t)(wave * 4 + t) * 512),
          16, 0, 0);
      __builtin_amdgcn_global_load_lds(
          (__attribute__((address_space(1))) void*)gb,
          (__attribute__((address_space(3))) void*)(Bs + (size_t)(wave * 4 + t) * 512),
          16, 0, 0);
    }
    __syncthreads();
    #pragma unroll
    for (int ks = 0; ks < 2; ++ks) {
      bf16x8 af[4], bfr[4];
      #pragma unroll
      for (int mt = 0; mt < 4; ++mt)
        af[mt] = *(const bf16x8*)(As + (wm + mt * 16 + lr) * 64
                                     + (((ks * 4 + quad) ^ rsw) * 8));
      #pragma unroll
      for (int nt = 0; nt < 4; ++nt)
        bfr[nt] = *(const bf16x8*)(Bs + (wn + nt * 16 + lr) * 64
                                      + (((ks * 4 + quad) ^ rsw) * 8));
      #pragma unroll
      for (int mt = 0; mt < 4; ++mt)
        #pragma unroll
        for (int nt = 0; nt < 4; ++nt)
          acc[mt][nt] = __builtin_amdgcn_mfma_f32_16x16x32_bf16(
              af[mt], bfr[nt], acc[mt][nt], 0, 0, 0);
    }
  }
  if (n0 < 1024) {
    #pragma unroll
    for (int mt = 0; mt < 4; ++mt)
      #pragma unroll
      for (int nt = 0; nt < 4; ++nt)
        #pragma unroll
        for (int j = 0; j < 4; ++j) {
          size_t m = m0 + wm + mt * 16 + quad * 4 + j;
          size_t n = n0 + wn + nt * 16 + lr;
          Kw[m * DIMC + n] = f2bf(acc[mt][nt][j]);
        }
  } else {
    #pragma unroll
    for (int mt = 0; mt < 4; ++mt)
      #pragma unroll
      for (int nt = 0; nt < 4; ++nt) {
        size_t m = m0 + wm + mt * 16 + quad * 4;
        int hcol = (int)(n0 + wn + nt * 16 + lr) - 1024;
        int h = hcol >> 6, dh = hcol & 63;
        int bb = (int)(m >> 9), r = (int)(m & 511);
        ushort o4[4];
        #pragma unroll
        for (int j = 0; j < 4; ++j) o4[j] = f2bf(acc[mt][nt][j]);
        *(ushort4*)(Vt + (((size_t)bb * HEADS + h) * 64 + dh) * RK + r) =
            *(const ushort4*)o4;
      }
  }
}

// ---------------- 8-phase 256^2 GEMM (Q-proj / O-proj) -----------------------
// C[16384][1024] = A[16384][1024] @ Bt[1024][1024]^T.  mode 0: bf16*QSCALE;
// mode 1: fp32.  512 thr = 8 waves (2Mx4N); per-wave C = 128x64 = 8mf x 4nf.
// K = 16 tiles of 64, each as 2 k-halves of 32. LDS: As/Bs[2 dbuf][2 kh][16KB].
// Schedule (derived; all region reuse barrier-protected):
//   iter I computes tiles t=2I (slot0, ph0-3) and t+1 (slot1, ph4-7);
//   phase p: [4A(+4B on even) ds_read | 1 half-stage issue] bar lgkm0 16MFMA
//            [vmcnt(8) on odd-phase END -- wait BEFORE trailing barrier so
//             all waves' staged data is landed before next phase reads] bar.
//   issues: ph0 A-kh1(t+1), ph1 B-kh1(t+1), ph2 A-kh0(t+2), ph3 B-kh0(t+2),
//           ph4 A-kh1(t+2), ph5 B-kh1(t+2), ph6 A-kh0(t+3), ph7 B-kh0(t+3).
//   Every region written only after its last reader's trailing barrier.
// LDS swizzle (rule #21 both-sides): logical byte L=row*64+k*2 stored at
// D = L ^ (((L>>7)&3)<<4) (involution); gload_lds dest linear, source
// pre-permuted (lane' = lane ^ ((lane>>3)&3)); reads apply same XOR ->
// 16 lanes hit 8 distinct bank groups (2-way = free).
__global__ __launch_bounds__(512, 2) void gemm256(const ushort* __restrict__ A,
    const ushort* __restrict__ Bt, void* __restrict__ Cv, const int mode) {
  __shared__ ushort As[32768];   // [dbuf2][kh2][8192]
  __shared__ ushort Bs[32768];
  const int tid  = threadIdx.x;
  const int wave = tid >> 6, lane = tid & 63;
  const int lr = lane & 15, quad = lane >> 4;
  const int bid = blockIdx.y * gridDim.x + blockIdx.x;   // grid (4, 64) = 256
  const int swz = (bid & 7) * 32 + (bid >> 3);           // bijective XCD swizzle
  const size_t m0 = (size_t)(swz >> 2) * 256;
  const size_t n0 = (size_t)(swz & 3) * 256;
  const int wm = (wave >> 2) * 128, wn = (wave & 3) * 64;

  // staging: wave stages rows [wave*32, wave*32+32), 2 loads/thread
  const int lp   = lane ^ ((lane >> 3) & 3);       // source lane permutation
  const int srow = wave * 32 + (lp >> 2);          // load1: srow + 16
  const int skc  = (lp & 3) * 8;                   // ushort col in 32-k half
  const int ld0  = wave * 1024 + lane * 8;         // linear LDS dest (ushorts)

  // read-side swizzled 16B-group offset (ushorts)
  const int qoff = (((quad * 16) ^ (((lr >> 1) & 3) << 4)) >> 1);

#define STG_(dst_, src_, base_, t_, kh_) do {                                  \
    const ushort* s_ = (src_) + ((size_t)((base_) + srow)) * DIMC              \
                     + (t_) * 64 + (kh_) * 32 + skc;                           \
    ushort* d_ = (dst_) + ((((t_) & 1) * 2 + (kh_)) * 8192) + ld0;             \
    __builtin_amdgcn_global_load_lds(                                          \
        (__attribute__((address_space(1))) void*)s_,                           \
        (__attribute__((address_space(3))) void*)d_, 16, 0, 0);                \
    __builtin_amdgcn_global_load_lds(                                          \
        (__attribute__((address_space(1))) void*)(s_ + (size_t)16 * DIMC),     \
        (__attribute__((address_space(3))) void*)(d_ + 512), 16, 0, 0);        \
  } while (0)

#define RDB4_(t_, kh_)                                                         \
    bfr[0] = *(const bf16x8*)(Bs + (((t_)&1)*2 + (kh_))*8192 + (wn +  0 + lr)*32 + qoff); \
    bfr[1] = *(const bf16x8*)(Bs + (((t_)&1)*2 + (kh_))*8192 + (wn + 16 + lr)*32 + qoff); \
    bfr[2] = *(const bf16x8*)(Bs + (((t_)&1)*2 + (kh_))*8192 + (wn + 32 + lr)*32 + qoff); \
    bfr[3] = *(const bf16x8*)(Bs + (((t_)&1)*2 + (kh_))*8192 + (wn + 48 + lr)*32 + qoff)

#define RDA4_(mb_, t_, kh_)                                                    \
    a0_ = *(const bf16x8*)(As + (((t_)&1)*2 + (kh_))*8192 + (wm + ((mb_)+0)*16 + lr)*32 + qoff); \
    a1_ = *(const bf16x8*)(As + (((t_)&1)*2 + (kh_))*8192 + (wm + ((mb_)+1)*16 + lr)*32 + qoff); \
    a2_ = *(const bf16x8*)(As + (((t_)&1)*2 + (kh_))*8192 + (wm + ((mb_)+2)*16 + lr)*32 + qoff); \
    a3_ = *(const bf16x8*)(As + (((t_)&1)*2 + (kh_))*8192 + (wm + ((mb_)+3)*16 + lr)*32 + qoff)

#define MF16_(mb_)                                                             \
    acc[(mb_)+0][0] = __builtin_amdgcn_mfma_f32_16x16x32_bf16(a0_, bfr[0], acc[(mb_)+0][0], 0,0,0); \
    acc[(mb_)+1][0] = __builtin_amdgcn_mfma_f32_16x16x32_bf16(a1_, bfr[0], acc[(mb_)+1][0], 0,0,0); \
    acc[(mb_)+2][0] = __builtin_amdgcn_mfma_f32_16x16x32_bf16(a2_, bfr[0], acc[(mb_)+2][0], 0,0,0); \
    acc[(mb_)+3][0] = __builtin_amdgcn_mfma_f32_16x16x32_bf16(a3_, bfr[0], acc[(mb_)+3][0], 0,0,0); \
    acc[(mb_)+0][1] = __builtin_amdgcn_mfma_f32_16x16x32_bf16(a0_, bfr[1], acc[(mb_)+0][1], 0,0,0); \
    acc[(mb_)+1][1] = __builtin_amdgcn_mfma_f32_16x16x32_bf16(a1_, bfr[1], acc[(mb_)+1][1], 0,0,0); \
    acc[(mb_)+2][1] = __builtin_amdgcn_mfma_f32_16x16x32_bf16(a2_, bfr[1], acc[(mb_)+2][1], 0,0,0); \
    acc[(mb_)+3][1] = __builtin_amdgcn_mfma_f32_16x16x32_bf16(a3_, bfr[1], acc[(mb_)+3][1], 0,0,0); \
    acc[(mb_)+0][2] = __builtin_amdgcn_mfma_f32_16x16x32_bf16(a0_, bfr[2], acc[(mb_)+0][2], 0,0,0); \
    acc[(mb_)+1][2] = __builtin_amdgcn_mfma_f32_16x16x32_bf16(a1_, bfr[2], acc[(mb_)+1][2], 0,0,0); \
    acc[(mb_)+2][2] = __builtin_amdgcn_mfma_f32_16x16x32_bf16(a2_, bfr[2], acc[(mb_)+2][2], 0,0,0); \
    acc[(mb_)+3][2] = __builtin_amdgcn_mfma_f32_16x16x32_bf16(a3_, bfr[2], acc[(mb_)+3][2], 0,0,0); \
    acc[(mb_)+0][3] = __builtin_amdgcn_mfma_f32_16x16x32_bf16(a0_, bfr[3], acc[(mb_)+0][3], 0,0,0); \
    acc[(mb_)+1][3] = __builtin_amdgcn_mfma_f32_16x16x32_bf16(a1_, bfr[3], acc[(mb_)+1][3], 0,0,0); \
    acc[(mb_)+2][3] = __builtin_amdgcn_mfma_f32_16x16x32_bf16(a2_, bfr[3], acc[(mb_)+2][3], 0,0,0); \
    acc[(mb_)+3][3] = __builtin_amdgcn_mfma_f32_16x16x32_bf16(a3_, bfr[3], acc[(mb_)+3][3], 0,0,0)

#define VMW8 asm volatile("s_waitcnt vmcnt(8)" ::: "memory")
#define VMW4 asm volatile("s_waitcnt vmcnt(4)" ::: "memory")
#define VMW0 asm volatile("s_waitcnt vmcnt(0)" ::: "memory")
#define VMNONE ((void)0)

#define PHASE_(t_, kh_, mb_, RDB_, TAILVM_, ...) do {                          \
    if (RDB_) { RDB4_(t_, kh_); }                                              \
    bf16x8 a0_, a1_, a2_, a3_;                                                 \
    RDA4_(mb_, t_, kh_);                                                       \
    __VA_ARGS__;                                                               \
    __builtin_amdgcn_s_barrier();                                              \
    asm volatile("s_waitcnt lgkmcnt(0)" ::: "memory");                         \
    __builtin_amdgcn_sched_barrier(0);                                         \
    __builtin_amdgcn_s_setprio(1);                                             \
    MF16_(mb_);                                                                \
    __builtin_amdgcn_s_setprio(0);                                             \
    TAILVM_;                                                                   \
    __builtin_amdgcn_s_barrier();                                              \
  } while (0)

  bf16x8 bfr[4];
  f32x4 acc[8][4] = {};

  // prologue: tile0 fully + tile1 kh0  (6 stages = 12 loads)
  STG_(As, A,  m0, 0, 0); STG_(Bs, Bt, n0, 0, 0);
  STG_(As, A,  m0, 0, 1); STG_(Bs, Bt, n0, 0, 1);
  STG_(As, A,  m0, 1, 0); STG_(Bs, Bt, n0, 1, 0);
  VMW8;                          // tile0-kh0 landed (8 newer loads allowed)
  __builtin_amdgcn_s_barrier();

  for (int I = 0; I < 7; ++I) {
    const int t = 2 * I;
    PHASE_(t,     0, 0, 1, VMNONE, STG_(As, A,  m0, t + 1, 1));
    PHASE_(t,     0, 4, 0, VMW8,   STG_(Bs, Bt, n0, t + 1, 1));
    PHASE_(t,     1, 0, 1, VMNONE, STG_(As, A,  m0, t + 2, 0));
    PHASE_(t,     1, 4, 0, VMW8,   STG_(Bs, Bt, n0, t + 2, 0));
    PHASE_(t + 1, 0, 0, 1, VMNONE, STG_(As, A,  m0, t + 2, 1));
    PHASE_(t + 1, 0, 4, 0, VMW8,   STG_(Bs, Bt, n0, t + 2, 1));
    PHASE_(t + 1, 1, 0, 1, VMNONE, STG_(As, A,  m0, t + 3, 0));
    PHASE_(t + 1, 1, 4, 0, VMW8,   STG_(Bs, Bt, n0, t + 3, 0));
  }
  // peeled last iteration (tiles 14,15): drain vmcnt 8 -> 4 -> 0
  PHASE_(14, 0, 0, 1, VMNONE, STG_(As, A,  m0, 15, 1));
  PHASE_(14, 0, 4, 0, VMW8,   STG_(Bs, Bt, n0, 15, 1));
  PHASE_(14, 1, 0, 1, VMNONE, VMNONE);
  PHASE_(14, 1, 4, 0, VMW4,   VMNONE);
  PHASE_(15, 0, 0, 1, VMNONE, VMNONE);
  PHASE_(15, 0, 4, 0, VMW0,   VMNONE);
  PHASE_(15, 1, 0, 1, VMNONE, VMNONE);
  PHASE_(15, 1, 4, 0, VMNONE, VMNONE);

#undef STG_
#undef RDB4_
#undef RDA4_
#undef MF16_
#undef PHASE_

  // C/D layout: n = lane&15, m = quad*4 + reg
  if (mode == 0) {
    ushort* C16 = (ushort*)Cv;
    #pragma unroll
    for (int mf = 0; mf < 8; ++mf)
      #pragma unroll
      for (int nf = 0; nf < 4; ++nf)
        #pragma unroll
        for (int j = 0; j < 4; ++j) {
          size_t m = m0 + wm + mf * 16 + quad * 4 + j;
          size_t n = n0 + wn + nf * 16 + lr;
          C16[m * DIMC + n] = f2bf(acc[mf][nf][j] * QSCALE);
        }
  } else {
    float* C32 = (float*)Cv;
    #pragma unroll
    for (int mf = 0; mf < 8; ++mf)
      #pragma unroll
      for (int nf = 0; nf < 4; ++nf)
        #pragma unroll
        for (int j = 0; j < 4; ++j) {
          size_t m = m0 + wm + mf * 16 + quad * 4 + j;
          size_t n = n0 + wn + nf * 16 + lr;
          C32[m * DIMC + n] = acc[mf][nf][j];
        }
  }
}

// ---------------- fused flash attention (S^T trick) --------------------------
// (byte-identical to R6/R7/R8 -- proven structure)
__global__ __launch_bounds__(256) void attn(ushort* __restrict__ QO,
    const ushort* __restrict__ K, const ushort* __restrict__ Vt) {
  __shared__ __align__(16) ushort Ks[128 * 64];
  __shared__ __align__(16) ushort Vs[64 * 128];
  const int tid  = threadIdx.x;
  const int wave = tid >> 6, lane = tid & 63;
  const int lr = lane & 15, quad = lane >> 4;
  const int b = blockIdx.z, h = blockIdx.y, qb = blockIdx.x;
  const int lsw = (lr & 7) << 3;

  bf16x8 bq[2];
  {
    size_t row = (size_t)b * LQ + qb * 64 + wave * 16 + lr;
    const ushort* qp = QO + row * DIMC + h * DHEAD + quad * 8;
    bq[0] = *(const bf16x8*)(qp);
    bq[1] = *(const bf16x8*)(qp + 32);
  }

  const int krow = tid >> 3, kcol = (tid & 7) * 8;
  const int vrow = tid >> 4, vcol = (tid & 15) * 8;
  const int kwsw = (krow & 7) << 3;
  const int vwsw = (vrow & 7) << 3;
  const ushort* Kbase = K  + ((size_t)b * RK) * DIMC + h * DHEAD;
  const ushort* Vbase = Vt + (((size_t)b * HEADS + h) * 64) * RK;

  uint4 kr0, kr1, kr2, kr3, vr0, vr1, vr2, vr3;
#define LOADK(rc_, i_) \
  (*(const uint4*)(Kbase + (size_t)((rc_) * 128 + (i_) * 32 + krow) * DIMC + kcol))
#define LOADV(rc_, i_) \
  (*(const uint4*)(Vbase + (size_t)((i_) * 16 + vrow) * RK + (rc_) * 128 + vcol))
#define ISSUE(rc_) do {                                      \
    kr0 = LOADK(rc_, 0); kr1 = LOADK(rc_, 1);                \
    kr2 = LOADK(rc_, 2); kr3 = LOADK(rc_, 3);                \
    vr0 = LOADV(rc_, 0); vr1 = LOADV(rc_, 1);                \
    vr2 = LOADV(rc_, 2); vr3 = LOADV(rc_, 3);                \
  } while (0)

  ISSUE(0);

  float mi = -1e30f, li = 0.f;
  f32x4 o[4] = {};

  for (int rc = 0; rc < 4; ++rc) {
    __syncthreads();
    *(uint4*)(Ks + ((((0 * 32 + krow) * 64) + kcol) ^ kwsw)) = kr0;
    *(uint4*)(Ks + ((((1 * 32 + krow) * 64) + kcol) ^ kwsw)) = kr1;
    *(uint4*)(Ks + ((((2 * 32 + krow) * 64) + kcol) ^ kwsw)) = kr2;
    *(uint4*)(Ks + ((((3 * 32 + krow) * 64) + kcol) ^ kwsw)) = kr3;
    *(uint4*)(Vs + ((((0 * 16 + vrow) * 128) + vcol) ^ vwsw)) = vr0;
    *(uint4*)(Vs + ((((1 * 16 + vrow) * 128) + vcol) ^ vwsw)) = vr1;
    *(uint4*)(Vs + ((((2 * 16 + vrow) * 128) + vcol) ^ vwsw)) = vr2;
    *(uint4*)(Vs + ((((3 * 16 + vrow) * 128) + vcol) ^ vwsw)) = vr3;
    __syncthreads();
    if (rc < 3) ISSUE(rc + 1);

    float s[8][4];
    __builtin_amdgcn_s_setprio(1);
    #pragma unroll
    for (int nt = 0; nt < 8; ++nt) {
      f32x4 acc = {};
      acc = __builtin_amdgcn_mfma_f32_16x16x32_bf16(
          *(const bf16x8*)(Ks + ((((nt * 16 + lr) * 64) + quad * 8) ^ lsw)),
          bq[0], acc, 0, 0, 0);
      acc = __builtin_amdgcn_mfma_f32_16x16x32_bf16(
          *(const bf16x8*)(Ks + ((((nt * 16 + lr) * 64) + quad * 8 + 32) ^ lsw)),
          bq[1], acc, 0, 0, 0);
      #pragma unroll
      for (int j = 0; j < 4; ++j) s[nt][j] = acc[j];
    }
    __builtin_amdgcn_s_setprio(0);

    float c0 = s[0][0], c1 = s[0][1], c2 = s[0][2], c3 = s[0][3];
    #pragma unroll
    for (int nt = 1; nt < 8; ++nt) {
      c0 = fmaxf(c0, s[nt][0]); c1 = fmaxf(c1, s[nt][1]);
      c2 = fmaxf(c2, s[nt][2]); c3 = fmaxf(c3, s[nt][3]);
    }
    float cm = fmaxf(fmaxf(c0, c1), fmaxf(c2, c3));
    cm = fmaxf(cm, __shfl_xor(cm, 16));
    cm = fmaxf(cm, __shfl_xor(cm, 32));

    if (!__all(cm - mi <= 8.f)) {
      float mnew = fmaxf(mi, cm);
      float alpha = exp2_fast(mi - mnew);
      mi = mnew;
      li *= alpha;
      float a_bc[4];
      #pragma unroll
      for (int j = 0; j < 4; ++j) a_bc[j] = __shfl(alpha, quad * 4 + j, 16);
      #pragma unroll
      for (int n2 = 0; n2 < 4; ++n2)
        #pragma unroll
        for (int j = 0; j < 4; ++j) o[n2][j] *= a_bc[j];
    }

    short4v pf[8];
    float r0 = 0.f, r1 = 0.f, r2 = 0.f, r3 = 0.f;
    #pragma unroll
    for (int nt = 0; nt < 8; ++nt) {
      float p0 = exp2_fast(s[nt][0] - mi);
      float p1 = exp2_fast(s[nt][1] - mi);
      float p2 = exp2_fast(s[nt][2] - mi);
      float p3 = exp2_fast(s[nt][3] - mi);
      r0 += p0; r1 += p1; r2 += p2; r3 += p3;
      pf[nt][0] = (short)f2bf(p0); pf[nt][1] = (short)f2bf(p1);
      pf[nt][2] = (short)f2bf(p2); pf[nt][3] = (short)f2bf(p3);
    }
    float rs = (r0 + r1) + (r2 + r3);
    rs += __shfl_xor(rs, 16);
    rs += __shfl_xor(rs, 32);
    li += rs;

    __builtin_amdgcn_s_setprio(1);
    #pragma unroll
    for (int kt = 0; kt < 8; ++kt)
      #pragma unroll
      for (int n2 = 0; n2 < 4; ++n2) {
        short4v bv = *(const short4v*)(
            Vs + ((((n2 * 16 + lr) * 128) + kt * 16 + quad * 4) ^ lsw));
        o[n2] = __builtin_amdgcn_mfma_f32_16x16x16bf16_1k(pf[kt], bv, o[n2], 0, 0, 0);
      }
    __builtin_amdgcn_s_setprio(0);
  }
#undef LOADK
#undef LOADV
#undef ISSUE

  float li_bc[4];
  #pragma unroll
  for (int j = 0; j < 4; ++j) li_bc[j] = __shfl(li, quad * 4 + j, 16);
  #pragma unroll
  for (int n2 = 0; n2 < 4; ++n2)
    #pragma unroll
    for (int j = 0; j < 4; ++j) {
      size_t row = (size_t)b * LQ + qb * 64 + wave * 16 + quad * 4 + j;
      QO[row * DIMC + h * DHEAD + n2 * 16 + lr] = f2bf(o[n2][j] / li_bc[j]);
    }
}

// ---------------- launch -----------------------------------------------------
extern "C" void kernel_launch(void* const* d_in, const int* in_sizes, int n_in,
                              void* d_out, int out_size, void* d_ws, size_t ws_size,
                              hipStream_t stream) {
  const float* x   = (const float*)d_in[0];
  const float* ctx = (const float*)d_in[1];

  // d_out scratch (fp32 out buffer = 67 MB; all dead before final GEMM):
  ushort* outs = (ushort*)d_out;
  ushort* xb   = outs;                               // 16777216
  ushort* ctxb = outs + (size_t)16777216;            //  2097152
  ushort* WqT  = outs + (size_t)18874368;            //  1048576
  ushort* WkT  = outs + (size_t)19922944;            //  1048576 (WvT contiguous)
  ushort* WvT  = outs + (size_t)20971520;            //  1048576
  ushort* Kw   = outs + (size_t)22020096;            //  2097152
  ushort* Vt_g = outs + (size_t)24117248;            //  2097152

  // ws: Qw (33.5 MB) | WoT (2.1 MB)
  ushort* ws  = (ushort*)d_ws;
  ushort* Qw  = ws;
  ushort* WoT = ws + (size_t)16384 * 1024;

  prep<<<13312, 256, 0, stream>>>(x, ctx, xb, ctxb,
      (const float*)d_in[2], (const float*)d_in[3], (const float*)d_in[4],
      (const float*)d_in[5], WqT, WkT, WvT, WoT);
  gemm_kv<<<dim3(16, 16), 256, 0, stream>>>(ctxb, WkT, Kw, Vt_g);
  gemm256<<<dim3(4, 64), 512, 0, stream>>>(xb, WqT, Qw, 0);
  attn<<<dim3(LQ / 64, HEADS, BATCH), 256, 0, stream>>>(Qw, Kw, Vt_g);
  gemm256<<<dim3(4, 64), 512, 0, stream>>>(Qw, WoT, (float*)d_out, 1);
}